// Round 7
// baseline (548.021 us; speedup 1.0000x reference)
//
#include <hip/hip_runtime.h>

// QuantizedLinear: out[m][n] = 0.01 * sum_k x[m][k]*(q[n][k]-8) + (0.01*0.047)*qbias[n]
// M=16384, N=4096, K=4096.
// R7: R6 pipeline (256x256, BK=64 zero-conflict XOR swizzle, A x3/B x2 ring,
// 1 barrier/K-tile, counted lgkm/vmcnt, flipped XCD swizzle) with
// mfma_f32_32x32x16_bf16 (2382 TF rate vs 2075; half the MFMA inst count).
// 4 phases = 4 k-steps of K=16; per phase: 6 ds_read prefetch + 2 gload + 8 MFMA.

typedef __bf16 bf16x8 __attribute__((ext_vector_type(8)));
typedef float f32x16 __attribute__((ext_vector_type(16)));
typedef unsigned short u16;
typedef u16 u16x4 __attribute__((ext_vector_type(4)));
typedef u16 u16x8 __attribute__((ext_vector_type(8)));

static constexpr int Kdim = 4096;
static constexpr int Ndim = 4096;
static constexpr int BM = 256, BN = 256, BK = 64;
static constexpr int NKT = Kdim / BK;          // 64 K-tiles
static constexpr int TBUF = BM * BK;           // 16384 halfwords = 32 KiB per buffer

__device__ __forceinline__ u16 f2bf(float f) {
  union { float f; unsigned u; } c; c.f = f;
  unsigned u = c.u;
  return (u16)((u + 0x7FFFu + ((u >> 16) & 1u)) >> 16);  // RNE
}

// ---- pre-pass 1: x fp32 -> bf16 ----
__global__ __launch_bounds__(256) void cvt_x_kernel(const float* __restrict__ x,
                                                    u16* __restrict__ xb, int n4) {
  int stride = gridDim.x * blockDim.x;
  for (int i = blockIdx.x * blockDim.x + threadIdx.x; i < n4; i += stride) {
    float4 v = reinterpret_cast<const float4*>(x)[i];
    u16x4 o;
    o.x = f2bf(v.x); o.y = f2bf(v.y); o.z = f2bf(v.z); o.w = f2bf(v.w);
    reinterpret_cast<u16x4*>(xb)[i] = o;
  }
}

// ---- pre-pass 2: packed nibbles -> bf16 integer weights (q-8), exact ----
__global__ __launch_bounds__(256) void dequant_w_kernel(const int* __restrict__ pw,
                                                        u16* __restrict__ wb, int n4) {
  int stride = gridDim.x * blockDim.x;
  for (int i = blockIdx.x * blockDim.x + threadIdx.x; i < n4; i += stride) {
    int4 v = reinterpret_cast<const int4*>(pw)[i];
    int a[4] = {v.x, v.y, v.z, v.w};
    u16x8 o;
#pragma unroll
    for (int j = 0; j < 4; ++j) {
      o[2 * j]     = f2bf((float)((a[j] & 15) - 8));
      o[2 * j + 1] = f2bf((float)(((a[j] >> 4) & 15) - 8));
    }
    reinterpret_cast<u16x8*>(wb)[i] = o;
  }
}

__device__ __forceinline__ void gload16(const u16* g, const u16* l) {
  __builtin_amdgcn_global_load_lds(
      (const __attribute__((address_space(1))) void*)g,
      (__attribute__((address_space(3))) void*)l,
      16, 0, 0);
}

// ---- main GEMM ----
__global__ __launch_bounds__(512, 2) void gemm_kernel(const u16* __restrict__ A,
                                                      const u16* __restrict__ B,
                                                      const int* __restrict__ qbias,
                                                      float* __restrict__ C,
                                                      int Ntiles) {
  extern __shared__ u16 smem[];
  u16* As = smem;                    // 3 x 256x64 = 96 KiB (ring of 3)
  u16* Bs = smem + 3 * TBUF;         // 2 x 256x64 = 64 KiB (ring of 2)

  const int tid = threadIdx.x;
  const int lane = tid & 63;
  const int wave = tid >> 6;
  const int wm = wave >> 2, wn = wave & 3;   // 2 (M) x 4 (N) waves, each 128x64

  // T1 (flipped): bx fast within XCD chunk -> A panel L2-resident per XCD.
  const int cpx = gridDim.x >> 3;
  const int bid = blockIdx.x;
  const int swz = (bid & 7) * cpx + (bid >> 3);
  const int bx = swz % Ntiles;
  const int by = swz / Ntiles;
  const int m0 = by * BM, n0 = bx * BN;

  // ---- staging geometry (source carries inverse of the read swizzle) ----
  const int srow = tid >> 3;
  const int fcol = (((tid & 7) ^ (srow & 7)) << 3);  // halfword col offset
  const u16* pa[4];
  const u16* pb[4];
#pragma unroll
  for (int i = 0; i < 4; ++i) {
    pa[i] = A + (size_t)(m0 + i * 64 + srow) * Kdim + fcol;
    pb[i] = B + (size_t)(n0 + i * 64 + srow) * Kdim + fcol;
  }
  const int wbase = (tid & 0x1C0) * 8;   // wave-uniform LDS halfword base (HW adds lane*16B)

  // ---- ds_read geometry: phys slot = s_log ^ (row&7); s_log = 2*kstep + (lane>>5) ----
  const int kb = lane >> 5;              // 0 or 1
  const int lx = lane & 7;
  const int es0 = ((0 + kb) ^ lx) << 3;  // kstep 0 slot offset (halfwords)
  const int es1 = ((2 + kb) ^ lx) << 3;  // kstep 1
  const int es2 = ((4 + kb) ^ lx) << 3;  // kstep 2
  const int es3 = ((6 + kb) ^ lx) << 3;  // kstep 3
  const int ar0 = (wm * 128 + (lane & 31)) * 64;   // A halfword row base (+2048 per mt)
  const int br0 = (wn * 64 + (lane & 31)) * 64;    // B halfword row base (+2048 per nt)

  f32x16 acc[4][2] = {};

  // ---- prologue: B(0), A(0), A(1); vmcnt(4) leaves A(1) in flight ----
#pragma unroll
  for (int i = 0; i < 4; ++i) gload16(pb[i], Bs + i * 4096 + wbase);
#pragma unroll
  for (int i = 0; i < 4; ++i) gload16(pa[i], As + i * 4096 + wbase);
#pragma unroll
  for (int i = 0; i < 4; ++i) gload16(pa[i] + BK, As + TBUF + i * 4096 + wbase);
  asm volatile("s_waitcnt vmcnt(4)" ::: "memory");
  __builtin_amdgcn_s_barrier();

#define READS(AF, BF, ES)                                                     \
    _Pragma("unroll")                                                         \
    for (int mt = 0; mt < 4; ++mt)                                            \
      AF[mt] = *(const bf16x8*)(aL + ar0 + mt * 2048 + (ES));                 \
    _Pragma("unroll")                                                         \
    for (int nt = 0; nt < 2; ++nt)                                            \
      BF[nt] = *(const bf16x8*)(bL + br0 + nt * 2048 + (ES));

#define MFMAS(AF, BF)                                                         \
    __builtin_amdgcn_sched_barrier(0);                                        \
    __builtin_amdgcn_s_setprio(1);                                            \
    _Pragma("unroll")                                                         \
    for (int mt = 0; mt < 4; ++mt)                                            \
      _Pragma("unroll")                                                       \
      for (int nt = 0; nt < 2; ++nt)                                          \
        acc[mt][nt] = __builtin_amdgcn_mfma_f32_32x32x16_bf16(                \
            AF[mt], BF[nt], acc[mt][nt], 0, 0, 0);                            \
    __builtin_amdgcn_s_setprio(0);

  int rbuf = 0;
  for (int t = 0; t < NKT; ++t) {
    const u16* aL = As + rbuf * TBUF;
    const u16* bL = Bs + (t & 1) * TBUF;
    const u16* aW = As + ((rbuf + 2) % 3) * TBUF;     // A(t+2) dest
    const u16* bW = Bs + ((t + 1) & 1) * TBUF;        // B(t+1) dest
    const bool stb = (t + 1) < NKT;
    const bool sta = (t + 2) < NKT;
    const int kob = (t + 1) * BK;
    const int koa = (t + 2) * BK;

    bf16x8 afA[4], bfA[2], afB[4], bfB[2];

    // ---- tile start: kstep0 frags (6 reads) ----
    READS(afA, bfA, es0)

    // ---- P0: prefetch kstep1; stage 2xB; MFMA kstep0 ----
    READS(afB, bfB, es1)
    if (stb) { gload16(pb[0] + kob, bW + 0 * 4096 + wbase);
               gload16(pb[1] + kob, bW + 1 * 4096 + wbase); }
    asm volatile("s_waitcnt lgkmcnt(6)" ::: "memory");
    MFMAS(afA, bfA)

    // ---- P1: prefetch kstep2; stage 2xB; MFMA kstep1 ----
    READS(afA, bfA, es2)
    if (stb) { gload16(pb[2] + kob, bW + 2 * 4096 + wbase);
               gload16(pb[3] + kob, bW + 3 * 4096 + wbase); }
    asm volatile("s_waitcnt lgkmcnt(6)" ::: "memory");
    MFMAS(afB, bfB)

    // ---- P2: prefetch kstep3; stage 2xA; MFMA kstep2 ----
    READS(afB, bfB, es3)
    if (sta) { gload16(pa[0] + koa, aW + 0 * 4096 + wbase);
               gload16(pa[1] + koa, aW + 1 * 4096 + wbase); }
    asm volatile("s_waitcnt lgkmcnt(6)" ::: "memory");
    MFMAS(afA, bfA)

    // ---- P3: stage 2xA; drain reads; MFMA kstep3 ----
    if (sta) { gload16(pa[2] + koa, aW + 2 * 4096 + wbase);
               gload16(pa[3] + koa, aW + 3 * 4096 + wbase); }
    asm volatile("s_waitcnt lgkmcnt(0)" ::: "memory");
    MFMAS(afB, bfB)
    __builtin_amdgcn_sched_barrier(0);

    // ---- boundary: A(t+1)+B(t+1) landed; A(t+2) (newest 4) stays in flight ----
    if (sta)      asm volatile("s_waitcnt vmcnt(4)" ::: "memory");
    else if (stb) asm volatile("s_waitcnt vmcnt(0)" ::: "memory");
    __builtin_amdgcn_s_barrier();

    rbuf = (rbuf == 2) ? 0 : rbuf + 1;
  }
#undef READS
#undef MFMAS

  // epilogue: 32x32 C/D layout col=lane&31, row=(reg&3)+8*(reg>>2)+4*(lane>>5)
  const float wscale = 0.01f;
  const float bscale = (float)(0.01 * 0.047);
  const int colb = n0 + wn * 64 + (lane & 31);
  const int rowb = m0 + wm * 128 + ((lane >> 5) << 2);
#pragma unroll
  for (int nt = 0; nt < 2; ++nt) {
    const int col = colb + nt * 32;
    const float bias = bscale * (float)qbias[col];
#pragma unroll
    for (int mt = 0; mt < 4; ++mt) {
#pragma unroll
      for (int reg = 0; reg < 16; ++reg) {
        const int row = rowb + mt * 32 + (reg & 3) + 8 * (reg >> 2);
        C[(size_t)row * Ndim + col] = wscale * acc[mt][nt][reg] + bias;
      }
    }
  }
}

extern "C" void kernel_launch(void* const* d_in, const int* in_sizes, int n_in,
                              void* d_out, int out_size, void* d_ws, size_t ws_size,
                              hipStream_t stream) {
  const float* x  = (const float*)d_in[0];
  const int*   pw = (const int*)d_in[1];
  const int*   qb = (const int*)d_in[2];
  float* out = (float*)d_out;

  const int M = in_sizes[0] / Kdim;  // 16384

  u16* xb = (u16*)d_ws;                                  // M*K bf16
  u16* wb = (u16*)((char*)d_ws + (size_t)M * Kdim * 2);  // N*K bf16

  cvt_x_kernel<<<2048, 256, 0, stream>>>(x, xb, M * Kdim / 4);
  dequant_w_kernel<<<1024, 256, 0, stream>>>(pw, wb, Ndim * Kdim / 8);

  const int Ntiles = Ndim / BN;                  // 16
  const int nwg = (M / BM) * Ntiles;             // 1024, multiple of 8
  static const size_t lds_bytes = 5u * TBUF * sizeof(u16);  // 160 KiB exactly
  (void)hipFuncSetAttribute((const void*)gemm_kernel,
                            hipFuncAttributeMaxDynamicSharedMemorySize,
                            (int)lds_bytes);
  gemm_kernel<<<nwg, 512, lds_bytes, stream>>>(xb, wb, qb, out, Ntiles);
}